// Round 1
// baseline (213.248 us; speedup 1.0000x reference)
//
#include <hip/hip_runtime.h>

// MultiScaleRoIAlign: torchvision-style FPN RoIAlign (aligned=false), SR=2, OUT=7.
// B=2, N=256 boxes/img, C=256, pyramid sizes 200/100/50/25, scales 1/4..1/32.
// One thread per output element (roi, c, ph, pw). Level assignment per
// LevelMapper: lvl = floor(4 + log2(sqrt(area)/224) + 1e-6), clipped [2,5].

#define ROI_OUT 7
#define ROI_C   256
#define ROI_N   256   // boxes per image
#define BINS    (ROI_OUT * ROI_OUT)   // 49

__global__ __launch_bounds__(256)
void msroi_kernel(const float* __restrict__ f0,
                  const float* __restrict__ f1,
                  const float* __restrict__ f2,
                  const float* __restrict__ f3,
                  const float* __restrict__ boxes,
                  float* __restrict__ out,
                  int total)
{
    int e = blockIdx.x * 256 + threadIdx.x;
    if (e >= total) return;

    int bin = e % BINS;
    int c   = (e / BINS) % ROI_C;
    int roi = e / (BINS * ROI_C);
    int b   = roi / ROI_N;

    // box (x1,y1,x2,y2) in image coords
    const float* bx = boxes + (size_t)roi * 4;
    float bx1 = bx[0], by1 = bx[1], bx2 = bx[2], by2 = bx[3];

    // FPN level assignment (float32 math to mirror the reference)
    float area = (bx2 - bx1) * (by2 - by1);
    float s    = sqrtf(area);
    float lvlf = floorf(4.0f + log2f(s * (1.0f / 224.0f)) + 1e-6f);
    lvlf = fminf(fmaxf(lvlf, 2.0f), 5.0f);
    int level = (int)lvlf - 2;

    const float* feat;
    int H, W;
    float scale;
    switch (level) {
        case 0:  feat = f0; H = 200; W = 200; scale = 0.25f;    break;
        case 1:  feat = f1; H = 100; W = 100; scale = 0.125f;   break;
        case 2:  feat = f2; H = 50;  W = 50;  scale = 0.0625f;  break;
        default: feat = f3; H = 25;  W = 25;  scale = 0.03125f; break;
    }

    float x1 = bx1 * scale;
    float y1 = by1 * scale;
    float roi_w = fmaxf(bx2 * scale - x1, 1.0f);
    float roi_h = fmaxf(by2 * scale - y1, 1.0f);
    float bin_w = roi_w * (1.0f / ROI_OUT);
    float bin_h = roi_h * (1.0f / ROI_OUT);

    int ph = bin / ROI_OUT;
    int pw = bin - ph * ROI_OUT;

    const float* plane = feat + ((size_t)(b * ROI_C + c)) * (size_t)(H * W);

    float Hf = (float)H, Wf = (float)W;
    float acc = 0.0f;

    #pragma unroll
    for (int sy = 0; sy < 2; ++sy) {
        // ys = y1 + bin_idx*bin_h + (sub)*bin_h/SR, sub = sy + 0.5
        float ys = y1 + (float)ph * bin_h + ((float)sy + 0.5f) * bin_h * 0.5f;
        float vy = (ys >= -1.0f && ys <= Hf) ? 1.0f : 0.0f;
        float y  = fminf(fmaxf(ys, 0.0f), Hf - 1.0f);
        int   y0 = (int)floorf(y);
        int   y1i = min(y0 + 1, H - 1);
        float ly = y - (float)y0;
        float hy = 1.0f - ly;
        int ro0 = y0 * W;
        int ro1 = y1i * W;

        #pragma unroll
        for (int sx = 0; sx < 2; ++sx) {
            float xs = x1 + (float)pw * bin_w + ((float)sx + 0.5f) * bin_w * 0.5f;
            float vx = (xs >= -1.0f && xs <= Wf) ? 1.0f : 0.0f;
            float x  = fminf(fmaxf(xs, 0.0f), Wf - 1.0f);
            int   x0 = (int)floorf(x);
            int   x1i = min(x0 + 1, W - 1);
            float lx = x - (float)x0;
            float hx = 1.0f - lx;

            float v00 = plane[ro0 + x0];
            float v01 = plane[ro0 + x1i];
            float v10 = plane[ro1 + x0];
            float v11 = plane[ro1 + x1i];

            float wv = vy * vx;   // branchless mask (indices are clipped-safe)
            acc += wv * (hy * (hx * v00 + lx * v01) + ly * (hx * v10 + lx * v11));
        }
    }

    out[e] = acc * 0.25f;   // mean over SR*SR = 4 samples (mask counted in mean)
}

extern "C" void kernel_launch(void* const* d_in, const int* in_sizes, int n_in,
                              void* d_out, int out_size, void* d_ws, size_t ws_size,
                              hipStream_t stream)
{
    const float* f0    = (const float*)d_in[0];
    const float* f1    = (const float*)d_in[1];
    const float* f2    = (const float*)d_in[2];
    const float* f3    = (const float*)d_in[3];
    const float* boxes = (const float*)d_in[4];
    float* out = (float*)d_out;

    int total = out_size;                 // 512 * 256 * 49
    int blocks = (total + 255) / 256;
    hipLaunchKernelGGL(msroi_kernel, dim3(blocks), dim3(256), 0, stream,
                       f0, f1, f2, f3, boxes, out, total);
}